// Round 1
// baseline (862.693 us; speedup 1.0000x reference)
//
#include <hip/hip_runtime.h>
#include <cstdint>
#include <cmath>

#define NN 8000      // nodes
#define NE 64000     // edges
#define DNE 128
#define DED 128
#define DXPD 64
#define NH 8
#define CDIM 640     // S * DNE
#define CHD 80       // CDIM / NH

// ---------------- workspace layout (float slots) ----------------
// phase 1-4 temporaries live inside the (later) coeff region [0, 40.96M)
static const size_t OFF_HQ    = 0;          // 1,024,000
static const size_t OFF_HK    = 1024000;    // 1,024,000
static const size_t OFF_VMID  = 2048000;    // 1,024,000
static const size_t OFF_SMID  = 3072000;    // 1,024,000
static const size_t OFF_GEOM  = 4096000;    // 8,192,000
static const size_t OFF_ALPHA = 12288000;   //   512,000
static const size_t OFF_COEFF = 0;          // 40,960,000 (E x 640)
static const size_t OFF_HV    = 40960000;   // 5,120,000
static const size_t OFF_HS    = 46080000;   // 5,120,000
static const size_t OFF_ATTN  = 51200000;   //   512,000
static const size_t OFF_CNT   = 51712000;   // 8000 ints
static const size_t OFF_CURSOR= 51720000;   // 8000 ints
static const size_t OFF_OFFS  = 51728000;   // 8001 ints
static const size_t OFF_EIDS  = 51744000;   // 64000 ints  -> end 51,808,000 floats (~207 MB)
// phase 7+ overlays (coeff dead after scatter)
static const size_t OFF_Q1N   = 0;          // 1,536,000
static const size_t OFF_K1N   = 1536000;    // 1,536,000
static const size_t OFF_Q2N   = 3072000;    // 2,560,000
static const size_t OFF_K2N   = 5632000;    // 2,560,000
static const size_t OFF_W     = 8192000;    // 4,096,000
static const size_t OFF_WMID  = 12288000;   // 4,096,000
static const size_t OFF_WOUT  = 16384000;   // 8,192,000
static const size_t OFF_TMID  = 24576000;   // 8,192,000
static const size_t OFF_TMLP  = 32768000;   // 8,192,000 -> 40,960,000

// ---------------- generic tiled fp32 GEMM: out = act(A@W + bias) ----------------
// A: MxK row-major, W: KxNc row-major, out: MxNc. M%64==0, Nc%64==0, K%16==0.
__global__ __launch_bounds__(256) void gemm_kernel(
    const float* __restrict__ A, const float* __restrict__ W,
    const float* __restrict__ bias, float* __restrict__ out,
    int M, int Nc, int K, int act)
{
    __shared__ float sA[16][65];
    __shared__ float sW[16][64];
    const int tid = threadIdx.x;
    const int bn = blockIdx.x, bm = blockIdx.y;
    const int tx = tid & 15, ty = tid >> 4;
    const int row0 = bm * 64, col0 = bn * 64;
    const int la_m = tid >> 2;
    const int la_k = (tid & 3) << 2;
    const int lw_k = tid >> 4;
    const int lw_n = (tid & 15) << 2;
    float acc[4][4] = {};
    for (int k0 = 0; k0 < K; k0 += 16) {
        float4 av = *(const float4*)(A + (size_t)(row0 + la_m) * K + (k0 + la_k));
        sA[la_k + 0][la_m] = av.x;
        sA[la_k + 1][la_m] = av.y;
        sA[la_k + 2][la_m] = av.z;
        sA[la_k + 3][la_m] = av.w;
        float4 wv = *(const float4*)(W + (size_t)(k0 + lw_k) * Nc + (col0 + lw_n));
        *(float4*)(&sW[lw_k][lw_n]) = wv;
        __syncthreads();
        #pragma unroll
        for (int kk = 0; kk < 16; ++kk) {
            float ar[4], br[4];
            #pragma unroll
            for (int q = 0; q < 4; ++q) { ar[q] = sA[kk][ty * 4 + q]; br[q] = sW[kk][tx * 4 + q]; }
            #pragma unroll
            for (int ii = 0; ii < 4; ++ii)
                #pragma unroll
                for (int jj = 0; jj < 4; ++jj)
                    acc[ii][jj] += ar[ii] * br[jj];
        }
        __syncthreads();
    }
    #pragma unroll
    for (int ii = 0; ii < 4; ++ii) {
        size_t orow = (size_t)(row0 + ty * 4 + ii) * Nc + col0;
        #pragma unroll
        for (int jj = 0; jj < 4; ++jj) {
            float v = acc[ii][jj];
            int cc = col0 + tx * 4 + jj;
            if (bias) v += bias[cc];
            if (act) v = v / (1.0f + expf(-v));   // silu
            out[orow + tx * 4 + jj] = v;
        }
    }
}

// ---------------- coeff GEMM: tp = t@Wrs + brs fused with coeff epilogue ----------------
// coeff[e,cd] = attn[e, cd/80] * hv[j[e],cd] + tp[e,cd] * hs[j[e],cd] * c[e]
__global__ __launch_bounds__(256) void coeff_gemm_kernel(
    const float* __restrict__ A /* t ExK */, const float* __restrict__ W /* Wrs KxNc */,
    const float* __restrict__ brs,
    const int* __restrict__ edge, const float* __restrict__ cvals,
    const float* __restrict__ attn, const float* __restrict__ hv, const float* __restrict__ hs,
    float* __restrict__ coeff, int K)
{
    const int Nc = CDIM;
    __shared__ float sA[16][65];
    __shared__ float sW[16][64];
    const int tid = threadIdx.x;
    const int bn = blockIdx.x, bm = blockIdx.y;
    const int tx = tid & 15, ty = tid >> 4;
    const int row0 = bm * 64, col0 = bn * 64;
    const int la_m = tid >> 2;
    const int la_k = (tid & 3) << 2;
    const int lw_k = tid >> 4;
    const int lw_n = (tid & 15) << 2;
    float acc[4][4] = {};
    for (int k0 = 0; k0 < K; k0 += 16) {
        float4 av = *(const float4*)(A + (size_t)(row0 + la_m) * K + (k0 + la_k));
        sA[la_k + 0][la_m] = av.x;
        sA[la_k + 1][la_m] = av.y;
        sA[la_k + 2][la_m] = av.z;
        sA[la_k + 3][la_m] = av.w;
        float4 wv = *(const float4*)(W + (size_t)(k0 + lw_k) * Nc + (col0 + lw_n));
        *(float4*)(&sW[lw_k][lw_n]) = wv;
        __syncthreads();
        #pragma unroll
        for (int kk = 0; kk < 16; ++kk) {
            float ar[4], br[4];
            #pragma unroll
            for (int q = 0; q < 4; ++q) { ar[q] = sA[kk][ty * 4 + q]; br[q] = sW[kk][tx * 4 + q]; }
            #pragma unroll
            for (int ii = 0; ii < 4; ++ii)
                #pragma unroll
                for (int jj = 0; jj < 4; ++jj)
                    acc[ii][jj] += ar[ii] * br[jj];
        }
        __syncthreads();
    }
    #pragma unroll
    for (int ii = 0; ii < 4; ++ii) {
        int e = row0 + ty * 4 + ii;
        int jn = edge[2 * e + 1];
        float ce = cvals[e];
        const float* hvr = hv + (size_t)jn * CDIM;
        const float* hsr = hs + (size_t)jn * CDIM;
        #pragma unroll
        for (int jj = 0; jj < 4; ++jj) {
            int cd = col0 + tx * 4 + jj;
            float tp = acc[ii][jj] + brs[cd];
            float at = attn[e * NH + cd / CHD];
            coeff[(size_t)e * CDIM + cd] = at * hvr[cd] + tp * hsr[cd] * ce;
        }
    }
}

// ---------------- CSR build ----------------
__global__ void zero_i32_kernel(int* a, int n) {
    int t = blockIdx.x * 256 + threadIdx.x;
    if (t < n) a[t] = 0;
}

__global__ void count_kernel(const int* __restrict__ edge, int* __restrict__ cnt, int E_) {
    int e = blockIdx.x * 256 + threadIdx.x;
    if (e < E_) atomicAdd(&cnt[edge[2 * e]], 1);
}

__global__ __launch_bounds__(1024) void scan_kernel(const int* __restrict__ cnt, int* __restrict__ offs, int n) {
    __shared__ int s[1024];
    int t = threadIdx.x;
    int base = t * 8;
    int loc[8];
    int sum = 0;
    #pragma unroll
    for (int q = 0; q < 8; ++q) {
        int idx = base + q;
        int v = (idx < n) ? cnt[idx] : 0;
        loc[q] = v;
        sum += v;
    }
    s[t] = sum;
    __syncthreads();
    for (int off = 1; off < 1024; off <<= 1) {
        int v = (t >= off) ? s[t - off] : 0;
        __syncthreads();
        s[t] += v;
        __syncthreads();
    }
    int run = s[t] - sum;   // exclusive prefix for this thread
    #pragma unroll
    for (int q = 0; q < 8; ++q) {
        int idx = base + q;
        if (idx < n) offs[idx] = run;
        run += loc[q];
    }
    if (t == 1023) offs[n] = s[1023];
}

__global__ void fill_kernel(const int* __restrict__ edge, const int* __restrict__ offs,
                            int* __restrict__ cursor, int* __restrict__ eids, int E_) {
    int e = blockIdx.x * 256 + threadIdx.x;
    if (e >= E_) return;
    int i = edge[2 * e];
    int pos = atomicAdd(&cursor[i], 1);
    eids[offs[i] + pos] = e;
}

// ---------------- alpha: per-edge per-head dot ----------------
__global__ __launch_bounds__(128) void alpha_kernel(
    const float* __restrict__ hq, const float* __restrict__ hk, const float* __restrict__ geom,
    const int* __restrict__ edge, float* __restrict__ alpha)
{
    int e = blockIdx.x;
    int d = threadIdx.x;
    int i = edge[2 * e], j = edge[2 * e + 1];
    float p = hq[(size_t)i * DNE + d] * hk[(size_t)j * DNE + d] * geom[(size_t)e * DNE + d];
    p += __shfl_xor(p, 1);
    p += __shfl_xor(p, 2);
    p += __shfl_xor(p, 4);
    p += __shfl_xor(p, 8);
    if ((d & 15) == 0) alpha[e * NH + (d >> 4)] = p;
}

// ---------------- per-node softmax over incoming edges ----------------
__global__ __launch_bounds__(64) void softmax_kernel(
    const float* __restrict__ alpha, const int* __restrict__ offs, const int* __restrict__ eids,
    float* __restrict__ attn)
{
    int node = blockIdx.x;
    int t = threadIdx.x;
    int g = t >> 3, hh = t & 7;   // 8 edge-groups x 8 heads
    int beg = offs[node], end = offs[node + 1];
    int deg = end - beg;
    __shared__ float sm[8][8];
    __shared__ float ss[8][8];
    float m = -1e9f;
    for (int p = beg + g; p < end; p += 8) {
        int e = eids[p];
        m = fmaxf(m, alpha[e * NH + hh]);
    }
    sm[g][hh] = m;
    __syncthreads();
    if (g == 0) {
        float mm = sm[0][hh];
        #pragma unroll
        for (int q = 1; q < 8; ++q) mm = fmaxf(mm, sm[q][hh]);
        sm[0][hh] = mm;
    }
    __syncthreads();
    float mx = sm[0][hh];
    float ssum = 0.f;
    for (int p = beg + g; p < end; p += 8) {
        int e = eids[p];
        ssum += expf(alpha[e * NH + hh] - mx);
    }
    ss[g][hh] = ssum;
    __syncthreads();
    if (g == 0) {
        float tot = 0.f;
        #pragma unroll
        for (int q = 0; q < 8; ++q) tot += ss[q][hh];
        ss[0][hh] = fmaxf(tot, 1e-12f);
    }
    __syncthreads();
    float den = ss[0][hh];
    float scale = sqrtf((float)deg) * 0.08838834764831845f;  // 1/sqrt(128)
    for (int p = beg + g; p < end; p += 8) {
        int e = eids[p];
        attn[e * NH + hh] = expf(alpha[e * NH + hh] - mx) / den * scale;
    }
}

// ---------------- per-node scatter accumulation (no atomics) ----------------
__global__ __launch_bounds__(128) void scatter_kernel(
    const float* __restrict__ coeff, const int* __restrict__ edge,
    const float* __restrict__ r1, const float* __restrict__ r2,
    const float* __restrict__ h, const float* __restrict__ X1, const float* __restrict__ X2,
    const int* __restrict__ offs, const int* __restrict__ eids,
    float* __restrict__ h_out, float* __restrict__ X1_out, float* __restrict__ X2_out)
{
    int n = blockIdx.x;
    int d = threadIdx.x;
    int beg = offs[n], end = offs[n + 1];
    float hacc = 0.f;
    float x1a[3] = {0.f, 0.f, 0.f};
    float x2a[5] = {0.f, 0.f, 0.f, 0.f, 0.f};
    for (int p = beg; p < end; ++p) {
        int e = eids[p];
        int j = edge[2 * e + 1];
        const float* crow = coeff + (size_t)e * CDIM;
        float c0  = crow[d];
        float od1 = crow[128 + d];
        float od2 = crow[256 + d];
        float ot1 = crow[384 + d];
        float ot2 = crow[512 + d];
        hacc += c0;
        #pragma unroll
        for (int a = 0; a < 3; ++a)
            x1a[a] += r1[e * 3 + a] * od1 + X1[((size_t)j * 3 + a) * DNE + d] * ot1;
        #pragma unroll
        for (int a = 0; a < 5; ++a)
            x2a[a] += r2[e * 5 + a] * od2 + X2[((size_t)j * 5 + a) * DNE + d] * ot2;
    }
    h_out[(size_t)n * DNE + d] = h[(size_t)n * DNE + d] + hacc;
    #pragma unroll
    for (int a = 0; a < 3; ++a) {
        size_t idx = ((size_t)n * 3 + a) * DNE + d;
        X1_out[idx] = X1[idx] + x1a[a];
    }
    #pragma unroll
    for (int a = 0; a < 5; ++a) {
        size_t idx = ((size_t)n * 5 + a) * DNE + d;
        X2_out[idx] = X2[idx] + x2a[a];
    }
}

// ---------------- w = sum_a rej(Q)[a,d] * rej(K)[a,d] ----------------
// Note: rej(x,-r) == rej(x,r), so K uses the same r as Q.
__global__ __launch_bounds__(256) void w_kernel(
    const float* __restrict__ Q1n, const float* __restrict__ Q2n,
    const float* __restrict__ K1n, const float* __restrict__ K2n,
    const int* __restrict__ edge, const float* __restrict__ r1, const float* __restrict__ r2,
    float* __restrict__ w, int E_)
{
    int e = blockIdx.x * 4 + (threadIdx.x >> 6);
    int d = threadIdx.x & 63;
    if (e >= E_) return;
    int i = edge[2 * e], j = edge[2 * e + 1];
    float q[8], k[8];
    #pragma unroll
    for (int a = 0; a < 3; ++a) {
        q[a] = Q1n[((size_t)i * 3 + a) * DXPD + d];
        k[a] = K1n[((size_t)j * 3 + a) * DXPD + d];
    }
    #pragma unroll
    for (int a = 0; a < 5; ++a) {
        q[3 + a] = Q2n[((size_t)i * 5 + a) * DXPD + d];
        k[3 + a] = K2n[((size_t)j * 5 + a) * DXPD + d];
    }
    float ra[3], rb[5];
    #pragma unroll
    for (int a = 0; a < 3; ++a) ra[a] = r1[e * 3 + a];
    #pragma unroll
    for (int a = 0; a < 5; ++a) rb[a] = r2[e * 5 + a];
    float dq1 = 0.f, dk1 = 0.f, dq2 = 0.f, dk2 = 0.f;
    #pragma unroll
    for (int a = 0; a < 3; ++a) { dq1 += q[a] * ra[a]; dk1 += k[a] * ra[a]; }
    #pragma unroll
    for (int a = 0; a < 5; ++a) { dq2 += q[3 + a] * rb[a]; dk2 += k[3 + a] * rb[a]; }
    float acc = 0.f;
    #pragma unroll
    for (int a = 0; a < 3; ++a) acc += (q[a] - dq1 * ra[a]) * (k[a] - dk1 * ra[a]);
    #pragma unroll
    for (int a = 0; a < 5; ++a) acc += (q[3 + a] - dq2 * rb[a]) * (k[3 + a] - dk2 * rb[a]);
    w[(size_t)e * DXPD + d] = acc;
}

// ---------------- t_out = t + wout * tmlp ----------------
__global__ void tout_kernel(const float* __restrict__ t, const float* __restrict__ wout,
                            const float* __restrict__ tmlp, float* __restrict__ t_out, int n) {
    int idx = blockIdx.x * 256 + threadIdx.x;
    if (idx < n) t_out[idx] = t[idx] + wout[idx] * tmlp[idx];
}

extern "C" void kernel_launch(void* const* d_in, const int* in_sizes, int n_in,
                              void* d_out, int out_size, void* d_ws, size_t ws_size,
                              hipStream_t stream)
{
    const float* h    = (const float*)d_in[0];
    const float* t    = (const float*)d_in[1];
    const float* X1   = (const float*)d_in[2];
    const float* X2   = (const float*)d_in[3];
    const float* r1   = (const float*)d_in[4];
    const float* r2   = (const float*)d_in[5];
    const float* c    = (const float*)d_in[6];
    const int*   edge = (const int*)d_in[7];
    const float* Wq   = (const float*)d_in[8];  const float* bq  = (const float*)d_in[9];
    const float* Wk   = (const float*)d_in[10]; const float* bk  = (const float*)d_in[11];
    const float* Wre  = (const float*)d_in[12]; const float* bre = (const float*)d_in[13];
    const float* Wv1  = (const float*)d_in[14]; const float* bv1 = (const float*)d_in[15];
    const float* Wv2  = (const float*)d_in[16]; const float* bv2 = (const float*)d_in[17];
    const float* Wrs  = (const float*)d_in[18]; const float* brs = (const float*)d_in[19];
    const float* Ws1  = (const float*)d_in[20]; const float* bs1 = (const float*)d_in[21];
    const float* Ws2  = (const float*)d_in[22]; const float* bs2 = (const float*)d_in[23];
    const float* Wvq  = (const float*)d_in[24];
    const float* Wvk1 = (const float*)d_in[25];
    const float* Wvk2 = (const float*)d_in[26];
    const float* Ww1  = (const float*)d_in[27]; const float* bw1 = (const float*)d_in[28];
    const float* Ww2  = (const float*)d_in[29]; const float* bw2 = (const float*)d_in[30];
    const float* Wt1  = (const float*)d_in[31]; const float* bt1 = (const float*)d_in[32];
    const float* Wt2  = (const float*)d_in[33]; const float* bt2 = (const float*)d_in[34];

    float* ws = (float*)d_ws;
    float* h_out  = (float*)d_out;
    float* t_out  = h_out + (size_t)NN * DNE;
    float* X1_out = t_out + (size_t)NE * DED;
    float* X2_out = X1_out + (size_t)NN * 3 * DNE;

    float* hq    = ws + OFF_HQ;
    float* hk    = ws + OFF_HK;
    float* vmid  = ws + OFF_VMID;
    float* smid  = ws + OFF_SMID;
    float* geom  = ws + OFF_GEOM;
    float* alpha = ws + OFF_ALPHA;
    float* coeff = ws + OFF_COEFF;
    float* hv    = ws + OFF_HV;
    float* hs    = ws + OFF_HS;
    float* attn  = ws + OFF_ATTN;
    int*   cnt    = (int*)(ws + OFF_CNT);
    int*   cursor = (int*)(ws + OFF_CURSOR);
    int*   offs   = (int*)(ws + OFF_OFFS);
    int*   eids   = (int*)(ws + OFF_EIDS);
    float* Q1n   = ws + OFF_Q1N;
    float* K1n   = ws + OFF_K1N;
    float* Q2n   = ws + OFF_Q2N;
    float* K2n   = ws + OFF_K2N;
    float* wbuf  = ws + OFF_W;
    float* wmid  = ws + OFF_WMID;
    float* wout  = ws + OFF_WOUT;
    float* tmid  = ws + OFF_TMID;
    float* tmlp  = ws + OFF_TMLP;

    auto gemm = [&](const float* A, const float* W, const float* bias, float* out,
                    int M, int Nc, int K, int act) {
        dim3 g(Nc / 64, M / 64);
        gemm_kernel<<<g, 256, 0, stream>>>(A, W, bias, out, M, Nc, K, act);
    };

    // ---- CSR build (cnt & cursor contiguous: zero both) ----
    zero_i32_kernel<<<(16000 + 255) / 256, 256, 0, stream>>>(cnt, 16000);
    count_kernel<<<(NE + 255) / 256, 256, 0, stream>>>(edge, cnt, NE);
    scan_kernel<<<1, 1024, 0, stream>>>(cnt, offs, NN);
    fill_kernel<<<(NE + 255) / 256, 256, 0, stream>>>(edge, offs, cursor, eids, NE);

    // ---- node projections ----
    gemm(h, Wq, bq, hq, NN, DNE, DNE, 0);
    gemm(h, Wk, bk, hk, NN, DNE, DNE, 0);
    gemm(h, Wv1, bv1, vmid, NN, DNE, DNE, 1);
    gemm(vmid, Wv2, bv2, hv, NN, CDIM, DNE, 0);
    gemm(h, Ws1, bs1, smid, NN, DNE, DNE, 1);
    gemm(smid, Ws2, bs2, hs, NN, CDIM, DNE, 0);
    // ---- edge geom ----
    gemm(t, Wre, bre, geom, NE, DNE, DED, 1);

    // ---- attention ----
    alpha_kernel<<<NE, 128, 0, stream>>>(hq, hk, geom, edge, alpha);
    softmax_kernel<<<NN, 64, 0, stream>>>(alpha, offs, eids, attn);

    // ---- coeff = attn*hv[j] + (t@Wrs+brs)*hs[j]*c ----
    {
        dim3 g(CDIM / 64, NE / 64);
        coeff_gemm_kernel<<<g, 256, 0, stream>>>(t, Wrs, brs, edge, c, attn, hv, hs, coeff, DED);
    }

    // ---- scatter into h_out, X1_out, X2_out ----
    scatter_kernel<<<NN, 128, 0, stream>>>(coeff, edge, r1, r2, h, X1, X2, offs, eids,
                                           h_out, X1_out, X2_out);

    // ---- Q/K projections from updated X ----
    gemm(X1_out, Wvq,  nullptr, Q1n, NN * 3, DXPD, DNE, 0);
    gemm(X2_out, Wvq,  nullptr, Q2n, NN * 5, DXPD, DNE, 0);
    gemm(X1_out, Wvk1, nullptr, K1n, NN * 3, DXPD, DNE, 0);
    gemm(X2_out, Wvk2, nullptr, K2n, NN * 5, DXPD, DNE, 0);

    // ---- w ----
    w_kernel<<<NE / 4, 256, 0, stream>>>(Q1n, Q2n, K1n, K2n, edge, r1, r2, wbuf, NE);

    // ---- edge MLPs ----
    gemm(wbuf, Ww1, bw1, wmid, NE, DXPD, DXPD, 1);
    gemm(wmid, Ww2, bw2, wout, NE, DED, DXPD, 0);
    gemm(t, Wt1, bt1, tmid, NE, DED, DED, 1);
    gemm(tmid, Wt2, bt2, tmlp, NE, DED, DED, 0);

    // ---- t_out ----
    tout_kernel<<<(NE * DED + 255) / 256, 256, 0, stream>>>(t, wout, tmlp, t_out, NE * DED);
}

// Round 2
// 585.545 us; speedup vs baseline: 1.4733x; 1.4733x over previous
//
#include <hip/hip_runtime.h>
#include <cstdint>
#include <cmath>

#define NN 8000
#define NE 64000
#define DNE 128
#define NHD 8
#define CDIM 640

typedef unsigned short u16;
typedef u16   u16x8 __attribute__((ext_vector_type(8)));
typedef __bf16 v8bf __attribute__((ext_vector_type(8)));
typedef float  v4f  __attribute__((ext_vector_type(4)));

static __device__ __forceinline__ u16 f2bf(float f) {
    unsigned int u = __float_as_uint(f);
    u += 0x7FFF + ((u >> 16) & 1);
    return (u16)(u >> 16);
}
static __device__ __forceinline__ float bf2f(u16 v) {
    return __uint_as_float(((unsigned int)v) << 16);
}

// ---------------- workspace byte offsets ----------------
constexpr size_t O_TBF   = 0;                          // 64000x128 bf16
constexpr size_t O_X1BF  = O_TBF   + 16384000;         // 24064x128
constexpr size_t O_X2BF  = O_X1BF  + 6160384;          // 40064x128
constexpr size_t O_X1OBF = O_X2BF  + 10256384;         // 24064x128
constexpr size_t O_X2OBF = O_X1OBF + 6160384;          // 40064x128
constexpr size_t O_WARE  = O_X2OBF + 10256384;         // 405504 u16
constexpr size_t O_CNT   = O_WARE  + 811008;
constexpr size_t O_CURS  = O_CNT   + 32000;
constexpr size_t O_OFFS  = O_CURS  + 32000;
constexpr size_t O_EIDS  = O_OFFS  + 32768;
constexpr size_t O_HV    = O_EIDS  + 256000;           // 8064x640 bf16
constexpr size_t O_HS    = O_HV    + 10321920;
constexpr size_t O_ATTN  = O_HS    + 10321920;         // 64000x8 f32
constexpr size_t O_TEMP  = O_ATTN  + 2048000;          // 81,920,000 overlay
// early-phase (dead before coeff GEMM):
constexpr size_t O_GEOM  = O_TEMP;
constexpr size_t O_HQ    = O_GEOM + 16384000;
constexpr size_t O_HK    = O_HQ   + 2064384;
constexpr size_t O_VMID  = O_HK   + 2064384;
constexpr size_t O_SMID  = O_VMID + 2064384;
constexpr size_t O_ALPHA = O_SMID + 2064384;
// coeff phase:
constexpr size_t O_COEFF = O_TEMP;                     // 64000x640 bf16
// post-scatter phase (coeff dead):
constexpr size_t O_Q1K1  = O_TEMP;                     // 24064x128
constexpr size_t O_Q2K2  = O_Q1K1 + 6160384;           // 40064x128
constexpr size_t O_WBUF  = O_Q2K2 + 10256384;          // 64000x64
constexpr size_t O_WMID  = O_WBUF + 8192000;           // 64000x64
constexpr size_t O_WOUT  = O_WMID + 8192000;           // 64000x128
constexpr size_t O_TMID  = O_WOUT + 16384000;          // 64000x128

// weight arena element offsets (u16)
// 0:Wq 1:Wk 2:Wre 3:Wv1 4:Ws1 5:Wt1 6:Wt2 7:Wv2 8:Wrs 9:Ws2 10:Ww1 11:Ww2 12:WA1 13:WA2
__device__ const int WOFFA[14] = {0,16384,32768,49152,65536,81920,98304,114688,196608,278528,360448,364544,372736,389120};

// ---------------- fused weight convert/transpose ----------------
struct WTArgs { const float* w[16]; };
__global__ void wtrans_all(WTArgs a, u16* __restrict__ ob) {
    int s = blockIdx.y;
    int id = blockIdx.x * 256 + threadIdx.x;
    if (s < 12) {
        int K = (s < 10) ? 128 : 64;
        int N = (s < 7) ? 128 : ((s < 10) ? 640 : ((s == 10) ? 64 : 128));
        if (id >= K * N) return;
        int k = id / N, n = id % N;
        ob[WOFFA[s] + (size_t)n * K + k] = f2bf(a.w[s][id]);
    } else {
        if (id >= 16384) return;
        int n = id >> 7, k = id & 127;
        const float* wa = a.w[s == 12 ? 12 : 14];
        const float* wb = a.w[s == 12 ? 13 : 15];
        ob[WOFFA[s] + id] = f2bf(n < 64 ? wa[k * 64 + n] : wb[k * 64 + (n - 64)]);
    }
}

// ---------------- fused activation fp32->bf16 convert (padded) ----------------
struct ConvArgs { const float* in[4]; u16* out[4]; };
__global__ void conv_all(ConvArgs a) {
    int s = blockIdx.y;
    int padr = (s == 0) ? 8064 : ((s == 1) ? 64000 : ((s == 2) ? 24064 : 40064));
    int realr = (s == 0) ? 8000 : ((s == 1) ? 64000 : ((s == 2) ? 24000 : 40000));
    int id4 = (blockIdx.x * 256 + threadIdx.x) * 4;
    if (id4 >= padr * 128) return;
    int row = id4 >> 7;
    float4 v = make_float4(0.f, 0.f, 0.f, 0.f);
    if (row < realr) v = *(const float4*)(a.in[s] + id4);
    u16* o = a.out[s] + id4;
    o[0] = f2bf(v.x); o[1] = f2bf(v.y); o[2] = f2bf(v.z); o[3] = f2bf(v.w);
}

// ---------------- bf16 MFMA GEMM, BM=128, BK=32 ----------------
// A: Mpad x K row-major bf16.  Bt: Ncols x K row-major bf16 (pre-transposed).
// MODE 0: out bf16 = (acc + bias?) [silu if act]
// MODE 2: coeff epilogue (bf16 out)
// MODE 3: t_out fp32 = tresid + bf(wmul) * (acc + bias)
template<int BN, int WROWS, int WCOLS, int MODE>
__global__ __launch_bounds__(256) void mm_bf16(
    const u16* __restrict__ A, const u16* __restrict__ Bt,
    const float* __restrict__ bias, void* __restrict__ out,
    int Ncols, int K, int act,
    const int* __restrict__ edge, const float* __restrict__ attn,
    const u16* __restrict__ hv, const u16* __restrict__ hs,
    const float* __restrict__ cvals,
    const float* __restrict__ tresid, const u16* __restrict__ wmul)
{
    constexpr int BM = 128, BK = 32, LDA = 40;
    constexpr int MT = BM / WROWS / 16;
    constexpr int NT = BN / WCOLS / 16;
    __shared__ u16 sA[BM * LDA];
    __shared__ u16 sB[BN * LDA];
    const int tid = threadIdx.x;
    const int wave = tid >> 6, lane = tid & 63;
    const int lane15 = lane & 15, quad = lane >> 4;
    const int wm = wave / WCOLS, wn = wave % WCOLS;
    const int row0 = blockIdx.y * BM, col0 = blockIdx.x * BN;
    const int arow = wm * (BM / WROWS);
    const int brow = wn * (BN / WCOLS);
    v4f acc[MT][NT] = {};
    for (int k0 = 0; k0 < K; k0 += BK) {
        #pragma unroll
        for (int ci = 0; ci < (BM * BK / 8) / 256; ++ci) {
            int cch = tid + ci * 256;
            int m = cch >> 2, ko = (cch & 3) * 8;
            u16x8 v = *(const u16x8*)(A + (size_t)(row0 + m) * K + k0 + ko);
            *(u16x8*)(&sA[m * LDA + ko]) = v;
        }
        #pragma unroll
        for (int ci = 0; ci < (BN * BK / 8) / 256; ++ci) {
            int cch = tid + ci * 256;
            int n = cch >> 2, ko = (cch & 3) * 8;
            u16x8 v = *(const u16x8*)(Bt + (size_t)(col0 + n) * K + k0 + ko);
            *(u16x8*)(&sB[n * LDA + ko]) = v;
        }
        __syncthreads();
        v8bf af[MT], bfr[NT];
        #pragma unroll
        for (int mt = 0; mt < MT; ++mt)
            af[mt] = __builtin_bit_cast(v8bf, *(const u16x8*)(&sA[(arow + mt * 16 + lane15) * LDA + quad * 8]));
        #pragma unroll
        for (int nt = 0; nt < NT; ++nt)
            bfr[nt] = __builtin_bit_cast(v8bf, *(const u16x8*)(&sB[(brow + nt * 16 + lane15) * LDA + quad * 8]));
        #pragma unroll
        for (int mt = 0; mt < MT; ++mt)
            #pragma unroll
            for (int nt = 0; nt < NT; ++nt)
                acc[mt][nt] = __builtin_amdgcn_mfma_f32_16x16x32_bf16(af[mt], bfr[nt], acc[mt][nt], 0, 0, 0);
        __syncthreads();
    }
    #pragma unroll
    for (int mt = 0; mt < MT; ++mt) {
        #pragma unroll
        for (int r = 0; r < 4; ++r) {
            int grow = row0 + arow + mt * 16 + quad * 4 + r;
            if (MODE == 2) {
                int e = grow;
                int jn = edge[2 * e + 1];
                float ce = cvals[e];
                const u16* hvr = hv + (size_t)jn * CDIM;
                const u16* hsr = hs + (size_t)jn * CDIM;
                u16* orow = (u16*)out + (size_t)e * CDIM;
                #pragma unroll
                for (int nt = 0; nt < NT; ++nt) {
                    int gcol = col0 + brow + nt * 16 + lane15;
                    float tp = acc[mt][nt][r] + bias[gcol];
                    float at = attn[e * NHD + gcol / 80];
                    float v = at * bf2f(hvr[gcol]) + tp * bf2f(hsr[gcol]) * ce;
                    orow[gcol] = f2bf(v);
                }
            } else if (MODE == 3) {
                size_t base = (size_t)grow * Ncols;
                #pragma unroll
                for (int nt = 0; nt < NT; ++nt) {
                    int gcol = col0 + brow + nt * 16 + lane15;
                    float v = acc[mt][nt][r] + bias[gcol];
                    ((float*)out)[base + gcol] = tresid[base + gcol] + bf2f(wmul[base + gcol]) * v;
                }
            } else {
                u16* orow = (u16*)out + (size_t)grow * Ncols;
                #pragma unroll
                for (int nt = 0; nt < NT; ++nt) {
                    int gcol = col0 + brow + nt * 16 + lane15;
                    float v = acc[mt][nt][r];
                    if (bias) v += bias[gcol];
                    if (act) v = v / (1.0f + expf(-v));
                    orow[gcol] = f2bf(v);
                }
            }
        }
    }
}

// ---------------- CSR build ----------------
__global__ void zero_i32_kernel(int* a, int n) {
    int t = blockIdx.x * 256 + threadIdx.x;
    if (t < n) a[t] = 0;
}
__global__ void count_kernel(const int* __restrict__ edge, int* __restrict__ cnt, int E_) {
    int e = blockIdx.x * 256 + threadIdx.x;
    if (e < E_) atomicAdd(&cnt[edge[2 * e]], 1);
}
__global__ __launch_bounds__(1024) void scan_kernel(const int* __restrict__ cnt, int* __restrict__ offs, int n) {
    __shared__ int s[1024];
    int t = threadIdx.x;
    int base = t * 8;
    int loc[8];
    int sum = 0;
    #pragma unroll
    for (int q = 0; q < 8; ++q) {
        int idx = base + q;
        int v = (idx < n) ? cnt[idx] : 0;
        loc[q] = v; sum += v;
    }
    s[t] = sum;
    __syncthreads();
    for (int off = 1; off < 1024; off <<= 1) {
        int v = (t >= off) ? s[t - off] : 0;
        __syncthreads();
        s[t] += v;
        __syncthreads();
    }
    int run = s[t] - sum;
    #pragma unroll
    for (int q = 0; q < 8; ++q) {
        int idx = base + q;
        if (idx < n) offs[idx] = run;
        run += loc[q];
    }
    if (t == 1023) offs[n] = s[1023];
}
__global__ void fill_kernel(const int* __restrict__ edge, const int* __restrict__ offs,
                            int* __restrict__ cursor, int* __restrict__ eids, int E_) {
    int e = blockIdx.x * 256 + threadIdx.x;
    if (e >= E_) return;
    int i = edge[2 * e];
    int pos = atomicAdd(&cursor[i], 1);
    eids[offs[i] + pos] = e;
}

// ---------------- alpha ----------------
__global__ __launch_bounds__(256) void alpha_kernel(
    const u16* __restrict__ hq, const u16* __restrict__ hk, const u16* __restrict__ geom,
    const int* __restrict__ edge, float* __restrict__ alpha)
{
    int e = blockIdx.x * 2 + (threadIdx.x >> 7);
    int d = threadIdx.x & 127;
    int i = edge[2 * e], j = edge[2 * e + 1];
    float p = bf2f(hq[(size_t)i * DNE + d]) * bf2f(hk[(size_t)j * DNE + d]) * bf2f(geom[(size_t)e * DNE + d]);
    p += __shfl_xor(p, 1);
    p += __shfl_xor(p, 2);
    p += __shfl_xor(p, 4);
    p += __shfl_xor(p, 8);
    if ((d & 15) == 0) alpha[e * NHD + (d >> 4)] = p;
}

// ---------------- per-node softmax ----------------
__global__ __launch_bounds__(64) void softmax_kernel(
    const float* __restrict__ alpha, const int* __restrict__ offs, const int* __restrict__ eids,
    float* __restrict__ attn)
{
    int node = blockIdx.x;
    int t = threadIdx.x;
    int g = t >> 3, hh = t & 7;
    int beg = offs[node], end = offs[node + 1];
    int deg = end - beg;
    __shared__ float sm[8][8];
    __shared__ float ss[8][8];
    float m = -1e9f;
    for (int p = beg + g; p < end; p += 8) {
        int e = eids[p];
        m = fmaxf(m, alpha[e * NHD + hh]);
    }
    sm[g][hh] = m;
    __syncthreads();
    if (g == 0) {
        float mm = sm[0][hh];
        #pragma unroll
        for (int q = 1; q < 8; ++q) mm = fmaxf(mm, sm[q][hh]);
        sm[0][hh] = mm;
    }
    __syncthreads();
    float mx = sm[0][hh];
    float ssum = 0.f;
    for (int p = beg + g; p < end; p += 8) {
        int e = eids[p];
        ssum += expf(alpha[e * NHD + hh] - mx);
    }
    ss[g][hh] = ssum;
    __syncthreads();
    if (g == 0) {
        float tot = 0.f;
        #pragma unroll
        for (int q = 0; q < 8; ++q) tot += ss[q][hh];
        ss[0][hh] = fmaxf(tot, 1e-12f);
    }
    __syncthreads();
    float den = ss[0][hh];
    float scale = sqrtf((float)deg) * 0.08838834764831845f;
    for (int p = beg + g; p < end; p += 8) {
        int e = eids[p];
        attn[e * NHD + hh] = expf(alpha[e * NHD + hh] - mx) / den * scale;
    }
}

// ---------------- per-node scatter accumulation ----------------
__global__ __launch_bounds__(128) void scatter_kernel(
    const u16* __restrict__ coeff, const int* __restrict__ edge,
    const float* __restrict__ r1, const float* __restrict__ r2,
    const float* __restrict__ h, const float* __restrict__ X1, const float* __restrict__ X2,
    const u16* __restrict__ X1bf, const u16* __restrict__ X2bf,
    const int* __restrict__ offs, const int* __restrict__ eids,
    float* __restrict__ h_out, float* __restrict__ X1_out, float* __restrict__ X2_out,
    u16* __restrict__ X1obf, u16* __restrict__ X2obf)
{
    int n = blockIdx.x;
    int d = threadIdx.x;
    int beg = offs[n], end = offs[n + 1];
    float hacc = 0.f;
    float x1a[3] = {0.f, 0.f, 0.f};
    float x2a[5] = {0.f, 0.f, 0.f, 0.f, 0.f};
    for (int p = beg; p < end; ++p) {
        int e = eids[p];
        int j = edge[2 * e + 1];
        const u16* crow = coeff + (size_t)e * CDIM;
        float c0  = bf2f(crow[d]);
        float od1 = bf2f(crow[128 + d]);
        float od2 = bf2f(crow[256 + d]);
        float ot1 = bf2f(crow[384 + d]);
        float ot2 = bf2f(crow[512 + d]);
        hacc += c0;
        #pragma unroll
        for (int a = 0; a < 3; ++a)
            x1a[a] += r1[e * 3 + a] * od1 + bf2f(X1bf[((size_t)j * 3 + a) * DNE + d]) * ot1;
        #pragma unroll
        for (int a = 0; a < 5; ++a)
            x2a[a] += r2[e * 5 + a] * od2 + bf2f(X2bf[((size_t)j * 5 + a) * DNE + d]) * ot2;
    }
    h_out[(size_t)n * DNE + d] = h[(size_t)n * DNE + d] + hacc;
    #pragma unroll
    for (int a = 0; a < 3; ++a) {
        size_t idx = ((size_t)n * 3 + a) * DNE + d;
        float v = X1[idx] + x1a[a];
        X1_out[idx] = v;
        X1obf[idx] = f2bf(v);
    }
    #pragma unroll
    for (int a = 0; a < 5; ++a) {
        size_t idx = ((size_t)n * 5 + a) * DNE + d;
        float v = X2[idx] + x2a[a];
        X2_out[idx] = v;
        X2obf[idx] = f2bf(v);
    }
}

// ---------------- w = sum_a rej(Q) . rej(K)  (rej(x,-r)==rej(x,r)) ----------------
__global__ __launch_bounds__(256) void w_kernel(
    const u16* __restrict__ QK1, const u16* __restrict__ QK2,
    const int* __restrict__ edge, const float* __restrict__ r1, const float* __restrict__ r2,
    u16* __restrict__ w, int E_)
{
    int e = blockIdx.x * 4 + (threadIdx.x >> 6);
    int d = threadIdx.x & 63;
    if (e >= E_) return;
    int i = edge[2 * e], j = edge[2 * e + 1];
    float q[8], k[8];
    #pragma unroll
    for (int a = 0; a < 3; ++a) {
        q[a] = bf2f(QK1[((size_t)i * 3 + a) * 128 + d]);
        k[a] = bf2f(QK1[((size_t)j * 3 + a) * 128 + 64 + d]);
    }
    #pragma unroll
    for (int a = 0; a < 5; ++a) {
        q[3 + a] = bf2f(QK2[((size_t)i * 5 + a) * 128 + d]);
        k[3 + a] = bf2f(QK2[((size_t)j * 5 + a) * 128 + 64 + d]);
    }
    float ra[3], rb[5];
    #pragma unroll
    for (int a = 0; a < 3; ++a) ra[a] = r1[e * 3 + a];
    #pragma unroll
    for (int a = 0; a < 5; ++a) rb[a] = r2[e * 5 + a];
    float dq1 = 0.f, dk1 = 0.f, dq2 = 0.f, dk2 = 0.f;
    #pragma unroll
    for (int a = 0; a < 3; ++a) { dq1 += q[a] * ra[a]; dk1 += k[a] * ra[a]; }
    #pragma unroll
    for (int a = 0; a < 5; ++a) { dq2 += q[3 + a] * rb[a]; dk2 += k[3 + a] * rb[a]; }
    float acc = 0.f;
    #pragma unroll
    for (int a = 0; a < 3; ++a) acc += (q[a] - dq1 * ra[a]) * (k[a] - dk1 * ra[a]);
    #pragma unroll
    for (int a = 0; a < 5; ++a) acc += (q[3 + a] - dq2 * rb[a]) * (k[3 + a] - dk2 * rb[a]);
    w[(size_t)e * 64 + d] = f2bf(acc);
}

extern "C" void kernel_launch(void* const* d_in, const int* in_sizes, int n_in,
                              void* d_out, int out_size, void* d_ws, size_t ws_size,
                              hipStream_t stream)
{
    const float* h    = (const float*)d_in[0];
    const float* t    = (const float*)d_in[1];
    const float* X1   = (const float*)d_in[2];
    const float* X2   = (const float*)d_in[3];
    const float* r1   = (const float*)d_in[4];
    const float* r2   = (const float*)d_in[5];
    const float* c    = (const float*)d_in[6];
    const int*   edge = (const int*)d_in[7];
    const float* Wq   = (const float*)d_in[8];  const float* bq  = (const float*)d_in[9];
    const float* Wk   = (const float*)d_in[10]; const float* bk  = (const float*)d_in[11];
    const float* Wre  = (const float*)d_in[12]; const float* bre = (const float*)d_in[13];
    const float* Wv1  = (const float*)d_in[14]; const float* bv1 = (const float*)d_in[15];
    const float* Wv2  = (const float*)d_in[16]; const float* bv2 = (const float*)d_in[17];
    const float* Wrs  = (const float*)d_in[18]; const float* brs = (const float*)d_in[19];
    const float* Ws1  = (const float*)d_in[20]; const float* bs1 = (const float*)d_in[21];
    const float* Ws2  = (const float*)d_in[22]; const float* bs2 = (const float*)d_in[23];
    const float* Wvq  = (const float*)d_in[24];
    const float* Wvk1 = (const float*)d_in[25];
    const float* Wvk2 = (const float*)d_in[26];
    const float* Ww1  = (const float*)d_in[27]; const float* bw1 = (const float*)d_in[28];
    const float* Ww2  = (const float*)d_in[29]; const float* bw2 = (const float*)d_in[30];
    const float* Wt1  = (const float*)d_in[31]; const float* bt1 = (const float*)d_in[32];
    const float* Wt2  = (const float*)d_in[33]; const float* bt2 = (const float*)d_in[34];

    char* ws = (char*)d_ws;
    float* h_out  = (float*)d_out;
    float* t_out  = h_out + (size_t)NN * DNE;
    float* X1_out = t_out + (size_t)NE * 128;
    float* X2_out = X1_out + (size_t)NN * 3 * DNE;

    u16* t_bf   = (u16*)(ws + O_TBF);
    u16* X1bf   = (u16*)(ws + O_X1BF);
    u16* X2bf   = (u16*)(ws + O_X2BF);
    u16* X1obf  = (u16*)(ws + O_X1OBF);
    u16* X2obf  = (u16*)(ws + O_X2OBF);
    u16* ware   = (u16*)(ws + O_WARE);
    int* cnt    = (int*)(ws + O_CNT);
    int* cursor = (int*)(ws + O_CURS);
    int* offs   = (int*)(ws + O_OFFS);
    int* eids   = (int*)(ws + O_EIDS);
    u16* hv_bf  = (u16*)(ws + O_HV);
    u16* hs_bf  = (u16*)(ws + O_HS);
    float* attn = (float*)(ws + O_ATTN);
    u16* geom   = (u16*)(ws + O_GEOM);
    u16* hq     = (u16*)(ws + O_HQ);
    u16* hk     = (u16*)(ws + O_HK);
    u16* vmid   = (u16*)(ws + O_VMID);
    u16* smid   = (u16*)(ws + O_SMID);
    float* alpha= (float*)(ws + O_ALPHA);
    u16* coeff  = (u16*)(ws + O_COEFF);
    u16* Q1K1   = (u16*)(ws + O_Q1K1);
    u16* Q2K2   = (u16*)(ws + O_Q2K2);
    u16* wbuf   = (u16*)(ws + O_WBUF);
    u16* wmid   = (u16*)(ws + O_WMID);
    u16* wout   = (u16*)(ws + O_WOUT);
    u16* tmid   = (u16*)(ws + O_TMID);

    // bf16 transposed weight sub-pointers
    u16* WqT  = ware + 0;      u16* WkT  = ware + 16384;  u16* WreT = ware + 32768;
    u16* Wv1T = ware + 49152;  u16* Ws1T = ware + 65536;  u16* Wt1T = ware + 81920;
    u16* Wt2T = ware + 98304;  u16* Wv2T = ware + 114688; u16* WrsT = ware + 196608;
    u16* Ws2T = ware + 278528; u16* Ww1T = ware + 360448; u16* Ww2T = ware + 364544;
    u16* WA1T = ware + 372736; u16* WA2T = ware + 389120;

    // ---- convert weights (1 launch) ----
    WTArgs wt;
    wt.w[0] = Wq;  wt.w[1] = Wk;  wt.w[2] = Wre; wt.w[3] = Wv1; wt.w[4] = Ws1;
    wt.w[5] = Wt1; wt.w[6] = Wt2; wt.w[7] = Wv2; wt.w[8] = Wrs; wt.w[9] = Ws2;
    wt.w[10] = Ww1; wt.w[11] = Ww2; wt.w[12] = Wvq; wt.w[13] = Wvk1; wt.w[14] = Wvq; wt.w[15] = Wvk2;
    wtrans_all<<<dim3(320, 14), 256, 0, stream>>>(wt, ware);

    // ---- convert activations (1 launch) ----
    ConvArgs ca;
    ca.in[0] = h;  ca.out[0] = hq; // placeholder; real below
    ca.in[0] = h;    ca.out[0] = (u16*)(ws + O_HQ); // temp: will convert h into hq slot? NO — need h_bf
    // h_bf lives in the HK slot temporarily? Use dedicated: reuse O_VMID before GEMMs? Simplest:
    // put h_bf into O_SMID region temporarily is unsafe. Use O_GEOM tail: h_bf at O_GEOM is
    // overwritten by geom GEMM later — but h_bf is only needed for the 6 node GEMMs which run
    // BEFORE the geom GEMM... geom GEMM runs after them. Place h_bf at O_ALPHA (alpha written later).
    u16* h_bf = (u16*)(ws + O_ALPHA);  // 8064*128*2 = 2,064,384 <= 2,048,000? NO (16K short). 
    // use O_ALPHA only if it fits: alpha region is 2,048,000 B < 2,064,384 B needed. Shift: place
    // h_bf right after O_TMID end inside TEMP (post region unused during early phase).
    h_bf = (u16*)(ws + O_TMID + 16384000);  // TEMP + 65,568,768 .. +67,633,152 < TEMP+81,920,000 OK
    ca.in[0] = h;  ca.out[0] = h_bf;
    ca.in[1] = t;  ca.out[1] = t_bf;
    ca.in[2] = X1; ca.out[2] = X1bf;
    ca.in[3] = X2; ca.out[3] = X2bf;
    conv_all<<<dim3(8000, 4), 256, 0, stream>>>(ca);

    // ---- CSR ----
    zero_i32_kernel<<<63, 256, 0, stream>>>(cnt, 16000);
    count_kernel<<<250, 256, 0, stream>>>(edge, cnt, NE);
    scan_kernel<<<1, 1024, 0, stream>>>(cnt, offs, NN);
    fill_kernel<<<250, 256, 0, stream>>>(edge, offs, cursor, eids, NE);

    const int* np = nullptr; const float* nf = nullptr; const u16* nu = nullptr;
    #define MMSTD(A_, B_, bias_, out_, NC_, K_, act_, gy_) \
        mm_bf16<128,2,2,0><<<dim3((NC_)/128, gy_), 256, 0, stream>>>((A_), (B_), (bias_), (out_), (NC_), (K_), (act_), np, nf, nu, nu, nf, nf, nu)

    // ---- node projections (M=8064 -> 63 blocks) ----
    MMSTD(h_bf, WqT,  bq,  hq,   128, 128, 0, 63);
    MMSTD(h_bf, WkT,  bk,  hk,   128, 128, 0, 63);
    MMSTD(h_bf, Wv1T, bv1, vmid, 128, 128, 1, 63);
    MMSTD(vmid, Wv2T, bv2, hv_bf, 640, 128, 0, 63);
    MMSTD(h_bf, Ws1T, bs1, smid, 128, 128, 1, 63);
    MMSTD(smid, Ws2T, bs2, hs_bf, 640, 128, 0, 63);
    // ---- geom ----
    MMSTD(t_bf, WreT, bre, geom, 128, 128, 1, 500);

    // ---- attention ----
    alpha_kernel<<<NE / 2, 256, 0, stream>>>(hq, hk, geom, edge, alpha);
    softmax_kernel<<<NN, 64, 0, stream>>>(alpha, offs, eids, attn);

    // ---- coeff GEMM (fused epilogue) ----
    mm_bf16<128,2,2,2><<<dim3(5, 500), 256, 0, stream>>>(
        t_bf, WrsT, brs, coeff, 640, 128, 0, edge, attn, hv_bf, hs_bf, c, nf, nu);

    // ---- scatter ----
    scatter_kernel<<<NN, 128, 0, stream>>>(coeff, edge, r1, r2, h, X1, X2, X1bf, X2bf,
                                           offs, eids, h_out, X1_out, X2_out, X1obf, X2obf);

    // ---- Q|K packed projections ----
    MMSTD(X1obf, WA1T, nullptr, Q1K1, 128, 128, 0, 188);
    MMSTD(X2obf, WA2T, nullptr, Q2K2, 128, 128, 0, 313);

    // ---- w ----
    w_kernel<<<NE / 4, 256, 0, stream>>>(Q1K1, Q2K2, edge, r1, r2, wbuf, NE);

    // ---- edge MLPs ----
    mm_bf16<64,4,1,0><<<dim3(1, 500), 256, 0, stream>>>(
        wbuf, Ww1T, bw1, wmid, 64, 64, 1, np, nf, nu, nu, nf, nf, nu);
    MMSTD(wmid, Ww2T, bw2, wout, 128, 64, 0, 500);
    MMSTD(t_bf, Wt1T, bt1, tmid, 128, 128, 1, 500);
    // tmlp with fused t_out epilogue
    mm_bf16<128,2,2,3><<<dim3(1, 500), 256, 0, stream>>>(
        tmid, Wt2T, bt2, t_out, 128, 128, 0, np, nf, nu, nu, nf, t, wout);
}

// Round 3
// 503.829 us; speedup vs baseline: 1.7123x; 1.1622x over previous
//
#include <hip/hip_runtime.h>
#include <cstdint>
#include <cmath>

#define NN 8000
#define NE 64000
#define DNE 128
#define NHD 8
#define CDIM 640

typedef unsigned short u16;
typedef u16   u16x8 __attribute__((ext_vector_type(8)));
typedef __bf16 v8bf __attribute__((ext_vector_type(8)));
typedef float  v4f  __attribute__((ext_vector_type(4)));

static __device__ __forceinline__ u16 f2bf(float f) {
    unsigned int u = __float_as_uint(f);
    u += 0x7FFF + ((u >> 16) & 1);
    return (u16)(u >> 16);
}
static __device__ __forceinline__ float bf2f(u16 v) {
    return __uint_as_float(((unsigned int)v) << 16);
}

// ---------------- workspace byte offsets ----------------
constexpr size_t O_TBF   = 0;                          // 64000x128 bf16
constexpr size_t O_X1BF  = 16384000;                   // 24064x128
constexpr size_t O_X2BF  = O_X1BF  + 6160384;          // 40064x128
constexpr size_t O_X1OBF = O_X2BF  + 10256384;
constexpr size_t O_X2OBF = O_X1OBF + 6160384;
constexpr size_t O_WARE  = O_X2OBF + 10256384;         // 405504 u16
constexpr size_t O_CNT   = O_WARE  + 811008;
constexpr size_t O_CURS  = O_CNT   + 32000;
constexpr size_t O_OFFS  = O_CURS  + 32000;
constexpr size_t O_EIDS  = O_OFFS  + 32768;
constexpr size_t O_HV    = O_EIDS  + 256000;           // 8064x640 bf16
constexpr size_t O_HS    = O_HV    + 10321920;
constexpr size_t O_ATTN  = O_HS    + 10321920;         // 64000x8 f32
constexpr size_t O_B512  = O_ATTN  + 2048000;          // 512 f32
constexpr size_t O_TEMP  = O_B512  + 2048;             // 81,920,000 overlay
// early phase (dead before coeff GEMM):
constexpr size_t O_QKVS  = O_TEMP;                     // 8064x512 bf16
constexpr size_t O_ALPHA = O_QKVS + 8257536;           // 64000x8 f32
constexpr size_t O_HBF   = O_ALPHA + 2048000;          // 8064x128 bf16
// coeff phase:
constexpr size_t O_COEFF = O_TEMP;                     // 64000x640 bf16
// post-scatter phase:
constexpr size_t O_Q1K1  = O_TEMP;                     // 24064x128 bf16
constexpr size_t O_Q2K2  = O_Q1K1 + 6160384;           // 40064x128 bf16
constexpr size_t O_WBUF  = O_Q2K2 + 10256384;          // 64000x64 bf16
constexpr size_t O_WOUT  = O_WBUF + 8192000;           // 64000x128 bf16

// weight arena u16 offsets (ordering: Wq,Wk,Wv1,Ws1 contiguous for fused QKVS GEMM)
// 0:Wq 1:Wk 2:Wv1 3:Ws1 4:Wre 5:Wt1 6:Wt2 7:Wv2 8:Wrs 9:Ws2 10:Ww1 11:Ww2 12:WA1 13:WA2
__device__ const int WOFFA[14] = {0,16384,32768,49152,65536,81920,98304,114688,196608,278528,360448,364544,372736,389120};

// ---------------- fused weight convert/transpose + bias pack ----------------
struct WTArgs { const float* w[16]; const float* b[4]; };
__global__ void wtrans_all(WTArgs a, u16* __restrict__ ob, float* __restrict__ bias512) {
    int s = blockIdx.y;
    int id = blockIdx.x * 256 + threadIdx.x;
    if (s < 12) {
        int K = (s < 10) ? 128 : 64;
        int N = (s < 7) ? 128 : ((s < 10) ? 640 : ((s == 10) ? 64 : 128));
        if (id >= K * N) return;
        int k = id / N, n = id % N;
        ob[WOFFA[s] + (size_t)n * K + k] = f2bf(a.w[s][id]);
    } else if (s < 14) {
        if (id >= 16384) return;
        int n = id >> 7, k = id & 127;
        const float* wa = a.w[s == 12 ? 12 : 14];
        const float* wb = a.w[s == 12 ? 13 : 15];
        ob[WOFFA[s] + id] = f2bf(n < 64 ? wa[k * 64 + n] : wb[k * 64 + (n - 64)]);
    } else {
        if (id >= 512) return;
        bias512[id] = a.b[id >> 7][id & 127];
    }
}

// ---------------- activation fp32->bf16 convert (padded rows zeroed) ----------------
struct ConvArgs { const float* in[4]; u16* out[4]; };
__global__ void conv_all(ConvArgs a) {
    int s = blockIdx.y;
    int padr = (s == 0) ? 8064 : ((s == 1) ? 64000 : ((s == 2) ? 24064 : 40064));
    int realr = (s == 0) ? 8000 : ((s == 1) ? 64000 : ((s == 2) ? 24000 : 40000));
    int id4 = (blockIdx.x * 256 + threadIdx.x) * 4;
    if (id4 >= padr * 128) return;
    int row = id4 >> 7;
    float4 v = make_float4(0.f, 0.f, 0.f, 0.f);
    if (row < realr) v = *(const float4*)(a.in[s] + id4);
    u16* o = a.out[s] + id4;
    o[0] = f2bf(v.x); o[1] = f2bf(v.y); o[2] = f2bf(v.z); o[3] = f2bf(v.w);
}

// ---------------- bf16 MFMA GEMM, BM=128, BN=128, BK=32 ----------------
// A: Mpad x K rows, row stride As. Bt: Ncols x K (pre-transposed).
// MODE 0: bf16 out = acc + bias?; act: 1=silu, 2=silu if gcol>=256
// MODE 2: coeff epilogue   MODE 4: alpha epilogue (geom never materialized)
template<int MODE>
__global__ __launch_bounds__(256) void mm_bf16(
    const u16* __restrict__ A, int As, const u16* __restrict__ Bt,
    const float* __restrict__ bias, void* __restrict__ out,
    int Ncols, int K, int act,
    const int* __restrict__ edge, const float* __restrict__ attn,
    const u16* __restrict__ hv, const u16* __restrict__ hs,
    const float* __restrict__ cvals)
{
    constexpr int BM = 128, BN = 128, BK = 32, LDA = 40;
    constexpr int MT = 4, NT = 4;
    __shared__ u16 sA[BM * LDA];
    __shared__ u16 sB[BN * LDA];
    const int tid = threadIdx.x;
    const int wave = tid >> 6, lane = tid & 63;
    const int lane15 = lane & 15, quad = lane >> 4;
    const int wm = wave >> 1, wn = wave & 1;
    const int row0 = blockIdx.y * BM, col0 = blockIdx.x * BN;
    const int arow = wm * 64, brow = wn * 64;
    v4f acc[MT][NT] = {};
    for (int k0 = 0; k0 < K; k0 += BK) {
        #pragma unroll
        for (int ci = 0; ci < 2; ++ci) {
            int cch = tid + ci * 256;
            int m = cch >> 2, ko = (cch & 3) * 8;
            *(u16x8*)(&sA[m * LDA + ko]) = *(const u16x8*)(A + (size_t)(row0 + m) * As + k0 + ko);
        }
        #pragma unroll
        for (int ci = 0; ci < 2; ++ci) {
            int cch = tid + ci * 256;
            int n = cch >> 2, ko = (cch & 3) * 8;
            *(u16x8*)(&sB[n * LDA + ko]) = *(const u16x8*)(Bt + (size_t)(col0 + n) * K + k0 + ko);
        }
        __syncthreads();
        v8bf af[MT], bfr[NT];
        #pragma unroll
        for (int mt = 0; mt < MT; ++mt)
            af[mt] = __builtin_bit_cast(v8bf, *(const u16x8*)(&sA[(arow + mt * 16 + lane15) * LDA + quad * 8]));
        #pragma unroll
        for (int nt = 0; nt < NT; ++nt)
            bfr[nt] = __builtin_bit_cast(v8bf, *(const u16x8*)(&sB[(brow + nt * 16 + lane15) * LDA + quad * 8]));
        #pragma unroll
        for (int mt = 0; mt < MT; ++mt)
            #pragma unroll
            for (int nt = 0; nt < NT; ++nt)
                acc[mt][nt] = __builtin_amdgcn_mfma_f32_16x16x32_bf16(af[mt], bfr[nt], acc[mt][nt], 0, 0, 0);
        __syncthreads();
    }
    #pragma unroll
    for (int mt = 0; mt < MT; ++mt) {
        #pragma unroll
        for (int r = 0; r < 4; ++r) {
            int grow = row0 + arow + mt * 16 + quad * 4 + r;
            if (MODE == 2) {
                int e = grow;
                int jn = edge[2 * e + 1];
                float ce = cvals[e];
                const u16* hvr = hv + (size_t)jn * CDIM;
                const u16* hsr = hs + (size_t)jn * CDIM;
                u16* orow = (u16*)out + (size_t)e * CDIM;
                #pragma unroll
                for (int nt = 0; nt < NT; ++nt) {
                    int gcol = col0 + brow + nt * 16 + lane15;
                    float tp = acc[mt][nt][r] + bias[gcol];
                    float at = attn[e * NHD + gcol / 80];
                    float v = at * bf2f(hvr[gcol]) + tp * bf2f(hsr[gcol]) * ce;
                    orow[gcol] = f2bf(v);
                }
            } else if (MODE == 4) {
                int e = grow;
                int i2 = edge[2 * e], j2 = edge[2 * e + 1];
                const u16* qb = hv + (size_t)i2 * 512;       // hq slice of qkvs
                const u16* kb = hv + (size_t)j2 * 512 + 128; // hk slice
                #pragma unroll
                for (int nt = 0; nt < NT; ++nt) {
                    int gcol = col0 + brow + nt * 16 + lane15;
                    float g = acc[mt][nt][r] + bias[gcol];
                    g = g / (1.0f + expf(-g));               // silu(geom)
                    float p = g * bf2f(qb[gcol]) * bf2f(kb[gcol]);
                    p += __shfl_xor(p, 1);
                    p += __shfl_xor(p, 2);
                    p += __shfl_xor(p, 4);
                    p += __shfl_xor(p, 8);
                    if (lane15 == 0)
                        ((float*)out)[(size_t)e * NHD + ((col0 + brow) >> 4) + nt] = p;
                }
            } else {
                u16* orow = (u16*)out + (size_t)grow * Ncols;
                #pragma unroll
                for (int nt = 0; nt < NT; ++nt) {
                    int gcol = col0 + brow + nt * 16 + lane15;
                    float v = acc[mt][nt][r];
                    if (bias) v += bias[gcol];
                    if (act == 1 || (act == 2 && gcol >= 256)) v = v / (1.0f + expf(-v));
                    orow[gcol] = f2bf(v);
                }
            }
        }
    }
}

// ---------------- chained MLP: wout = silu(w@W1+b1)@W2+b2 (K=64 chain) ----------------
__global__ __launch_bounds__(256) void wchain_kernel(
    const u16* __restrict__ wbuf, const u16* __restrict__ W1T, const u16* __restrict__ W2T,
    const float* __restrict__ b1, const float* __restrict__ b2, u16* __restrict__ wout)
{
    __shared__ u16 sw[128 * 72];
    __shared__ u16 sm[128 * 72];
    __shared__ u16 sW1[64 * 72];
    __shared__ u16 sW2[128 * 72];
    const int tid = threadIdx.x;
    const int wave = tid >> 6, lane = tid & 63;
    const int lane15 = lane & 15, quad = lane >> 4;
    const int row0 = blockIdx.x * 128;
    #pragma unroll
    for (int ci = 0; ci < 4; ++ci) {
        int cch = tid + ci * 256;
        int m = cch >> 3, ko = (cch & 7) * 8;
        *(u16x8*)(&sw[m * 72 + ko]) = *(const u16x8*)(wbuf + (size_t)(row0 + m) * 64 + ko);
    }
    #pragma unroll
    for (int ci = 0; ci < 2; ++ci) {
        int cch = tid + ci * 256;
        int n = cch >> 3, ko = (cch & 7) * 8;
        *(u16x8*)(&sW1[n * 72 + ko]) = *(const u16x8*)(W1T + (size_t)n * 64 + ko);
    }
    #pragma unroll
    for (int ci = 0; ci < 4; ++ci) {
        int cch = tid + ci * 256;
        int n = cch >> 3, ko = (cch & 7) * 8;
        *(u16x8*)(&sW2[n * 72 + ko]) = *(const u16x8*)(W2T + (size_t)n * 64 + ko);
    }
    __syncthreads();
    // phase 1: mid = silu(w@W1+b1): 128x64, wave -> rows wave*32..+31
    v4f a1[2][4] = {};
    #pragma unroll
    for (int kk = 0; kk < 2; ++kk) {
        int k0 = kk * 32;
        v8bf af[2], bfr[4];
        #pragma unroll
        for (int mt = 0; mt < 2; ++mt)
            af[mt] = __builtin_bit_cast(v8bf, *(const u16x8*)(&sw[(wave * 32 + mt * 16 + lane15) * 72 + k0 + quad * 8]));
        #pragma unroll
        for (int nt = 0; nt < 4; ++nt)
            bfr[nt] = __builtin_bit_cast(v8bf, *(const u16x8*)(&sW1[(nt * 16 + lane15) * 72 + k0 + quad * 8]));
        #pragma unroll
        for (int mt = 0; mt < 2; ++mt)
            #pragma unroll
            for (int nt = 0; nt < 4; ++nt)
                a1[mt][nt] = __builtin_amdgcn_mfma_f32_16x16x32_bf16(af[mt], bfr[nt], a1[mt][nt], 0, 0, 0);
    }
    #pragma unroll
    for (int mt = 0; mt < 2; ++mt)
        #pragma unroll
        for (int r = 0; r < 4; ++r) {
            int mrow = wave * 32 + mt * 16 + quad * 4 + r;
            #pragma unroll
            for (int nt = 0; nt < 4; ++nt) {
                int mcol = nt * 16 + lane15;
                float v = a1[mt][nt][r] + b1[mcol];
                v = v / (1.0f + expf(-v));
                sm[mrow * 72 + mcol] = f2bf(v);
            }
        }
    __syncthreads();
    // phase 2: wout = mid@W2+b2: 128x128
    const int wm = wave >> 1, wn = wave & 1;
    const int arow = wm * 64, brow = wn * 64;
    v4f a2[4][4] = {};
    #pragma unroll
    for (int kk = 0; kk < 2; ++kk) {
        int k0 = kk * 32;
        v8bf af[4], bfr[4];
        #pragma unroll
        for (int mt = 0; mt < 4; ++mt)
            af[mt] = __builtin_bit_cast(v8bf, *(const u16x8*)(&sm[(arow + mt * 16 + lane15) * 72 + k0 + quad * 8]));
        #pragma unroll
        for (int nt = 0; nt < 4; ++nt)
            bfr[nt] = __builtin_bit_cast(v8bf, *(const u16x8*)(&sW2[(brow + nt * 16 + lane15) * 72 + k0 + quad * 8]));
        #pragma unroll
        for (int mt = 0; mt < 4; ++mt)
            #pragma unroll
            for (int nt = 0; nt < 4; ++nt)
                a2[mt][nt] = __builtin_amdgcn_mfma_f32_16x16x32_bf16(af[mt], bfr[nt], a2[mt][nt], 0, 0, 0);
    }
    #pragma unroll
    for (int mt = 0; mt < 4; ++mt)
        #pragma unroll
        for (int r = 0; r < 4; ++r) {
            int grow = row0 + arow + mt * 16 + quad * 4 + r;
            #pragma unroll
            for (int nt = 0; nt < 4; ++nt) {
                int gcol = brow + nt * 16 + lane15;
                wout[(size_t)grow * 128 + gcol] = f2bf(a2[mt][nt][r] + b2[gcol]);
            }
        }
}

// ---------------- chained MLP: t_out = t + wout * (silu(t@Wt1+b1)@Wt2+b2) ----------------
__global__ __launch_bounds__(256) void tchain_kernel(
    const u16* __restrict__ tbf, const u16* __restrict__ W1T, const u16* __restrict__ W2T,
    const float* __restrict__ b1, const float* __restrict__ b2,
    const float* __restrict__ tin, const u16* __restrict__ wout,
    float* __restrict__ t_out)
{
    constexpr int LDA = 136;
    __shared__ u16 sA[128 * LDA];   // t tile, later mid
    __shared__ u16 sW[128 * 72];    // weight K-half
    const int tid = threadIdx.x;
    const int wave = tid >> 6, lane = tid & 63;
    const int lane15 = lane & 15, quad = lane >> 4;
    const int wm = wave >> 1, wn = wave & 1;
    const int arow = wm * 64, brow = wn * 64;
    const int row0 = blockIdx.x * 128;
    #pragma unroll
    for (int ci = 0; ci < 8; ++ci) {
        int cch = tid + ci * 256;
        int m = cch >> 4, ko = (cch & 15) * 8;
        *(u16x8*)(&sA[m * LDA + ko]) = *(const u16x8*)(tbf + (size_t)(row0 + m) * 128 + ko);
    }
    v4f acc[4][4] = {};
    #pragma unroll
    for (int kh = 0; kh < 2; ++kh) {
        __syncthreads();
        #pragma unroll
        for (int ci = 0; ci < 4; ++ci) {
            int cch = tid + ci * 256;
            int n = cch >> 3, ko = (cch & 7) * 8;
            *(u16x8*)(&sW[n * 72 + ko]) = *(const u16x8*)(W1T + (size_t)n * 128 + kh * 64 + ko);
        }
        __syncthreads();
        #pragma unroll
        for (int kk = 0; kk < 2; ++kk) {
            int k0 = kh * 64 + kk * 32;
            v8bf af[4], bfr[4];
            #pragma unroll
            for (int mt = 0; mt < 4; ++mt)
                af[mt] = __builtin_bit_cast(v8bf, *(const u16x8*)(&sA[(arow + mt * 16 + lane15) * LDA + k0 + quad * 8]));
            #pragma unroll
            for (int nt = 0; nt < 4; ++nt)
                bfr[nt] = __builtin_bit_cast(v8bf, *(const u16x8*)(&sW[(brow + nt * 16 + lane15) * 72 + kk * 32 + quad * 8]));
            #pragma unroll
            for (int mt = 0; mt < 4; ++mt)
                #pragma unroll
                for (int nt = 0; nt < 4; ++nt)
                    acc[mt][nt] = __builtin_amdgcn_mfma_f32_16x16x32_bf16(af[mt], bfr[nt], acc[mt][nt], 0, 0, 0);
        }
    }
    __syncthreads();    // all t-tile reads done
    #pragma unroll
    for (int mt = 0; mt < 4; ++mt)
        #pragma unroll
        for (int r = 0; r < 4; ++r) {
            int mrow = arow + mt * 16 + quad * 4 + r;
            #pragma unroll
            for (int nt = 0; nt < 4; ++nt) {
                int mcol = brow + nt * 16 + lane15;
                float v = acc[mt][nt][r] + b1[mcol];
                v = v / (1.0f + expf(-v));
                sA[mrow * LDA + mcol] = f2bf(v);
            }
        }
    v4f acc2[4][4] = {};
    #pragma unroll
    for (int kh = 0; kh < 2; ++kh) {
        __syncthreads();
        #pragma unroll
        for (int ci = 0; ci < 4; ++ci) {
            int cch = tid + ci * 256;
            int n = cch >> 3, ko = (cch & 7) * 8;
            *(u16x8*)(&sW[n * 72 + ko]) = *(const u16x8*)(W2T + (size_t)n * 128 + kh * 64 + ko);
        }
        __syncthreads();
        #pragma unroll
        for (int kk = 0; kk < 2; ++kk) {
            int k0 = kh * 64 + kk * 32;
            v8bf af[4], bfr[4];
            #pragma unroll
            for (int mt = 0; mt < 4; ++mt)
                af[mt] = __builtin_bit_cast(v8bf, *(const u16x8*)(&sA[(arow + mt * 16 + lane15) * LDA + k0 + quad * 8]));
            #pragma unroll
            for (int nt = 0; nt < 4; ++nt)
                bfr[nt] = __builtin_bit_cast(v8bf, *(const u16x8*)(&sW[(brow + nt * 16 + lane15) * 72 + kk * 32 + quad * 8]));
            #pragma unroll
            for (int mt = 0; mt < 4; ++mt)
                #pragma unroll
                for (int nt = 0; nt < 4; ++nt)
                    acc2[mt][nt] = __builtin_amdgcn_mfma_f32_16x16x32_bf16(af[mt], bfr[nt], acc2[mt][nt], 0, 0, 0);
        }
    }
    #pragma unroll
    for (int mt = 0; mt < 4; ++mt)
        #pragma unroll
        for (int r = 0; r < 4; ++r) {
            int grow = row0 + arow + mt * 16 + quad * 4 + r;
            size_t base = (size_t)grow * 128;
            #pragma unroll
            for (int nt = 0; nt < 4; ++nt) {
                int gcol = brow + nt * 16 + lane15;
                float v = acc2[mt][nt][r] + b2[gcol];
                t_out[base + gcol] = tin[base + gcol] + bf2f(wout[base + gcol]) * v;
            }
        }
}

// ---------------- CSR build ----------------
__global__ void zero_i32_kernel(int* a, int n) {
    int t = blockIdx.x * 256 + threadIdx.x;
    if (t < n) a[t] = 0;
}
__global__ void count_kernel(const int* __restrict__ edge, int* __restrict__ cnt, int E_) {
    int e = blockIdx.x * 256 + threadIdx.x;
    if (e < E_) atomicAdd(&cnt[edge[2 * e]], 1);
}
__global__ __launch_bounds__(1024) void scan_kernel(const int* __restrict__ cnt, int* __restrict__ offs, int n) {
    __shared__ int s[1024];
    int t = threadIdx.x;
    int base = t * 8;
    int loc[8];
    int sum = 0;
    #pragma unroll
    for (int q = 0; q < 8; ++q) {
        int idx = base + q;
        int v = (idx < n) ? cnt[idx] : 0;
        loc[q] = v; sum += v;
    }
    s[t] = sum;
    __syncthreads();
    for (int off = 1; off < 1024; off <<= 1) {
        int v = (t >= off) ? s[t - off] : 0;
        __syncthreads();
        s[t] += v;
        __syncthreads();
    }
    int run = s[t] - sum;
    #pragma unroll
    for (int q = 0; q < 8; ++q) {
        int idx = base + q;
        if (idx < n) offs[idx] = run;
        run += loc[q];
    }
    if (t == 1023) offs[n] = s[1023];
}
__global__ void fill_kernel(const int* __restrict__ edge, const int* __restrict__ offs,
                            int* __restrict__ cursor, int* __restrict__ eids, int E_) {
    int e = blockIdx.x * 256 + threadIdx.x;
    if (e >= E_) return;
    int i = edge[2 * e];
    int pos = atomicAdd(&cursor[i], 1);
    eids[offs[i] + pos] = e;
}

// ---------------- per-node softmax ----------------
__global__ __launch_bounds__(64) void softmax_kernel(
    const float* __restrict__ alpha, const int* __restrict__ offs, const int* __restrict__ eids,
    float* __restrict__ attn)
{
    int node = blockIdx.x;
    int t = threadIdx.x;
    int g = t >> 3, hh = t & 7;
    int beg = offs[node], end = offs[node + 1];
    int deg = end - beg;
    __shared__ float sm[8][8];
    __shared__ float ss[8][8];
    float m = -1e9f;
    for (int p = beg + g; p < end; p += 8) {
        int e = eids[p];
        m = fmaxf(m, alpha[e * NHD + hh]);
    }
    sm[g][hh] = m;
    __syncthreads();
    if (g == 0) {
        float mm = sm[0][hh];
        #pragma unroll
        for (int q = 1; q < 8; ++q) mm = fmaxf(mm, sm[q][hh]);
        sm[0][hh] = mm;
    }
    __syncthreads();
    float mx = sm[0][hh];
    float ssum = 0.f;
    for (int p = beg + g; p < end; p += 8) {
        int e = eids[p];
        ssum += expf(alpha[e * NHD + hh] - mx);
    }
    ss[g][hh] = ssum;
    __syncthreads();
    if (g == 0) {
        float tot = 0.f;
        #pragma unroll
        for (int q = 0; q < 8; ++q) tot += ss[q][hh];
        ss[0][hh] = fmaxf(tot, 1e-12f);
    }
    __syncthreads();
    float den = ss[0][hh];
    float scale = sqrtf((float)deg) * 0.08838834764831845f;
    for (int p = beg + g; p < end; p += 8) {
        int e = eids[p];
        attn[e * NHD + hh] = expf(alpha[e * NHD + hh] - mx) / den * scale;
    }
}

// ---------------- per-node scatter accumulation ----------------
__global__ __launch_bounds__(128) void scatter_kernel(
    const u16* __restrict__ coeff, const int* __restrict__ edge,
    const float* __restrict__ r1, const float* __restrict__ r2,
    const float* __restrict__ h, const float* __restrict__ X1, const float* __restrict__ X2,
    const u16* __restrict__ X1bf, const u16* __restrict__ X2bf,
    const int* __restrict__ offs, const int* __restrict__ eids,
    float* __restrict__ h_out, float* __restrict__ X1_out, float* __restrict__ X2_out,
    u16* __restrict__ X1obf, u16* __restrict__ X2obf)
{
    int n = blockIdx.x;
    int d = threadIdx.x;
    int beg = offs[n], end = offs[n + 1];
    float hacc = 0.f;
    float x1a[3] = {0.f, 0.f, 0.f};
    float x2a[5] = {0.f, 0.f, 0.f, 0.f, 0.f};
    for (int p = beg; p < end; ++p) {
        int e = eids[p];
        int j = edge[2 * e + 1];
        const u16* crow = coeff + (size_t)e * CDIM;
        float c0  = bf2f(crow[d]);
        float od1 = bf2f(crow[128 + d]);
        float od2 = bf2f(crow[256 + d]);
        float ot1 = bf2f(crow[384 + d]);
        float ot2 = bf2f(crow[512 + d]);
        hacc += c0;
        #pragma unroll
        for (int a = 0; a < 3; ++a)
            x1a[a] += r1[e * 3 + a] * od1 + bf2f(X1bf[((size_t)j * 3 + a) * DNE + d]) * ot1;
        #pragma unroll
        for (int a = 0; a < 5; ++a)
            x2a[a] += r2[e * 5 + a] * od2 + bf2f(X2bf[((size_t)j * 5 + a) * DNE + d]) * ot2;
    }
    h_out[(size_t)n * DNE + d] = h[(size_t)n * DNE + d] + hacc;
    #pragma unroll
    for (int a = 0; a < 3; ++a) {
        size_t idx = ((size_t)n * 3 + a) * DNE + d;
        float v = X1[idx] + x1a[a];
        X1_out[idx] = v;
        X1obf[idx] = f2bf(v);
    }
    #pragma unroll
    for (int a = 0; a < 5; ++a) {
        size_t idx = ((size_t)n * 5 + a) * DNE + d;
        float v = X2[idx] + x2a[a];
        X2_out[idx] = v;
        X2obf[idx] = f2bf(v);
    }
}

// ---------------- w = sum_a rej(Q) . rej(K)  (rej(x,-r)==rej(x,r)) ----------------
__global__ __launch_bounds__(256) void w_kernel(
    const u16* __restrict__ QK1, const u16* __restrict__ QK2,
    const int* __restrict__ edge, const float* __restrict__ r1, const float* __restrict__ r2,
    u16* __restrict__ w, int E_)
{
    int e = blockIdx.x * 4 + (threadIdx.x >> 6);
    int d = threadIdx.x & 63;
    if (e >= E_) return;
    int i = edge[2 * e], j = edge[2 * e + 1];
    float q[8], k[8];
    #pragma unroll
    for (int a = 0; a < 3; ++a) {
        q[a] = bf2f(QK1[((size_t)i * 3 + a) * 128 + d]);
        k[a] = bf2f(QK1[((size_t)j * 3 + a) * 128 + 64 + d]);
    }
    #pragma unroll
    for (int a = 0; a < 5; ++a) {
        q[3 + a] = bf2f(QK2[((size_t)i * 5 + a) * 128 + d]);
        k[3 + a] = bf2f(QK2[((size_t)j * 5 + a) * 128 + 64 + d]);
    }
    float ra[3], rb[5];
    #pragma unroll
    for (int a = 0; a < 3; ++a) ra[a] = r1[e * 3 + a];
    #pragma unroll
    for (int a = 0; a < 5; ++a) rb[a] = r2[e * 5 + a];
    float dq1 = 0.f, dk1 = 0.f, dq2 = 0.f, dk2 = 0.f;
    #pragma unroll
    for (int a = 0; a < 3; ++a) { dq1 += q[a] * ra[a]; dk1 += k[a] * ra[a]; }
    #pragma unroll
    for (int a = 0; a < 5; ++a) { dq2 += q[3 + a] * rb[a]; dk2 += k[3 + a] * rb[a]; }
    float acc = 0.f;
    #pragma unroll
    for (int a = 0; a < 3; ++a) acc += (q[a] - dq1 * ra[a]) * (k[a] - dk1 * ra[a]);
    #pragma unroll
    for (int a = 0; a < 5; ++a) acc += (q[3 + a] - dq2 * rb[a]) * (k[3 + a] - dk2 * rb[a]);
    w[(size_t)e * 64 + d] = f2bf(acc);
}

extern "C" void kernel_launch(void* const* d_in, const int* in_sizes, int n_in,
                              void* d_out, int out_size, void* d_ws, size_t ws_size,
                              hipStream_t stream)
{
    const float* h    = (const float*)d_in[0];
    const float* t    = (const float*)d_in[1];
    const float* X1   = (const float*)d_in[2];
    const float* X2   = (const float*)d_in[3];
    const float* r1   = (const float*)d_in[4];
    const float* r2   = (const float*)d_in[5];
    const float* c    = (const float*)d_in[6];
    const int*   edge = (const int*)d_in[7];
    const float* Wq   = (const float*)d_in[8];  const float* bq  = (const float*)d_in[9];
    const float* Wk   = (const float*)d_in[10]; const float* bk  = (const float*)d_in[11];
    const float* Wre  = (const float*)d_in[12]; const float* bre = (const float*)d_in[13];
    const float* Wv1  = (const float*)d_in[14]; const float* bv1 = (const float*)d_in[15];
    const float* Wv2  = (const float*)d_in[16]; const float* bv2 = (const float*)d_in[17];
    const float* Wrs  = (const float*)d_in[18]; const float* brs = (const float*)d_in[19];
    const float* Ws1  = (const float*)d_in[20]; const float* bs1 = (const float*)d_in[21];
    const float* Ws2  = (const float*)d_in[22]; const float* bs2 = (const float*)d_in[23];
    const float* Wvq  = (const float*)d_in[24];
    const float* Wvk1 = (const float*)d_in[25];
    const float* Wvk2 = (const float*)d_in[26];
    const float* Ww1  = (const float*)d_in[27]; const float* bw1 = (const float*)d_in[28];
    const float* Ww2  = (const float*)d_in[29]; const float* bw2 = (const float*)d_in[30];
    const float* Wt1  = (const float*)d_in[31]; const float* bt1 = (const float*)d_in[32];
    const float* Wt2  = (const float*)d_in[33]; const float* bt2 = (const float*)d_in[34];

    char* ws = (char*)d_ws;
    float* h_out  = (float*)d_out;
    float* t_out  = h_out + (size_t)NN * DNE;
    float* X1_out = t_out + (size_t)NE * 128;
    float* X2_out = X1_out + (size_t)NN * 3 * DNE;

    u16* t_bf   = (u16*)(ws + O_TBF);
    u16* X1bf   = (u16*)(ws + O_X1BF);
    u16* X2bf   = (u16*)(ws + O_X2BF);
    u16* X1obf  = (u16*)(ws + O_X1OBF);
    u16* X2obf  = (u16*)(ws + O_X2OBF);
    u16* ware   = (u16*)(ws + O_WARE);
    int* cnt    = (int*)(ws + O_CNT);
    int* cursor = (int*)(ws + O_CURS);
    int* offs   = (int*)(ws + O_OFFS);
    int* eids   = (int*)(ws + O_EIDS);
    u16* hv_bf  = (u16*)(ws + O_HV);
    u16* hs_bf  = (u16*)(ws + O_HS);
    float* attn = (float*)(ws + O_ATTN);
    float* bias512 = (float*)(ws + O_B512);
    u16* qkvs   = (u16*)(ws + O_QKVS);
    float* alpha= (float*)(ws + O_ALPHA);
    u16* h_bf   = (u16*)(ws + O_HBF);
    u16* coeff  = (u16*)(ws + O_COEFF);
    u16* Q1K1   = (u16*)(ws + O_Q1K1);
    u16* Q2K2   = (u16*)(ws + O_Q2K2);
    u16* wbuf   = (u16*)(ws + O_WBUF);
    u16* wout   = (u16*)(ws + O_WOUT);

    u16* WqkvsT = ware + 0;       // [Wq|Wk|Wv1|Ws1]T : 512 x 128
    u16* WreT = ware + 65536;
    u16* Wt1T = ware + 81920;
    u16* Wt2T = ware + 98304;
    u16* Wv2T = ware + 114688;
    u16* WrsT = ware + 196608;
    u16* Ws2T = ware + 278528;
    u16* Ww1T = ware + 360448;
    u16* Ww2T = ware + 364544;
    u16* WA1T = ware + 372736;
    u16* WA2T = ware + 389120;

    // ---- weights + bias pack ----
    WTArgs wt;
    wt.w[0] = Wq;  wt.w[1] = Wk;  wt.w[2] = Wv1; wt.w[3] = Ws1; wt.w[4] = Wre;
    wt.w[5] = Wt1; wt.w[6] = Wt2; wt.w[7] = Wv2; wt.w[8] = Wrs; wt.w[9] = Ws2;
    wt.w[10] = Ww1; wt.w[11] = Ww2; wt.w[12] = Wvq; wt.w[13] = Wvk1; wt.w[14] = Wvq; wt.w[15] = Wvk2;
    wt.b[0] = bq; wt.b[1] = bk; wt.b[2] = bv1; wt.b[3] = bs1;
    wtrans_all<<<dim3(320, 15), 256, 0, stream>>>(wt, ware, bias512);

    // ---- activations -> bf16 ----
    ConvArgs ca;
    ca.in[0] = h;  ca.out[0] = h_bf;
    ca.in[1] = t;  ca.out[1] = t_bf;
    ca.in[2] = X1; ca.out[2] = X1bf;
    ca.in[3] = X2; ca.out[3] = X2bf;
    conv_all<<<dim3(8000, 4), 256, 0, stream>>>(ca);

    // ---- CSR ----
    zero_i32_kernel<<<63, 256, 0, stream>>>(cnt, 16000);
    count_kernel<<<250, 256, 0, stream>>>(edge, cnt, NE);
    scan_kernel<<<1, 1024, 0, stream>>>(cnt, offs, NN);
    fill_kernel<<<250, 256, 0, stream>>>(edge, offs, cursor, eids, NE);

    const int* np = nullptr; const float* nf = nullptr; const u16* nu = nullptr;

    // ---- fused node projections: qkvs = h @ [Wq|Wk|Wv1|Ws1] (silu on v1/s1 cols) ----
    mm_bf16<0><<<dim3(4, 63), 256, 0, stream>>>(h_bf, 128, WqkvsT, bias512, qkvs,
                                                512, 128, 2, np, nf, nu, nu, nf);
    // ---- hv / hs from strided slices ----
    mm_bf16<0><<<dim3(5, 63), 256, 0, stream>>>(qkvs + 256, 512, Wv2T, bv2, hv_bf,
                                                640, 128, 0, np, nf, nu, nu, nf);
    mm_bf16<0><<<dim3(5, 63), 256, 0, stream>>>(qkvs + 384, 512, Ws2T, bs2, hs_bf,
                                                640, 128, 0, np, nf, nu, nu, nf);
    // ---- geom GEMM with fused alpha epilogue (geom never materialized) ----
    mm_bf16<4><<<dim3(1, 500), 256, 0, stream>>>(t_bf, 128, WreT, bre, alpha,
                                                 128, 128, 0, edge, nf, qkvs, nu, nf);
    softmax_kernel<<<NN, 64, 0, stream>>>(alpha, offs, eids, attn);

    // ---- coeff GEMM (fused epilogue) ----
    mm_bf16<2><<<dim3(5, 500), 256, 0, stream>>>(t_bf, 128, WrsT, brs, coeff,
                                                 640, 128, 0, edge, attn, hv_bf, hs_bf, c);

    // ---- scatter ----
    scatter_kernel<<<NN, 128, 0, stream>>>(coeff, edge, r1, r2, h, X1, X2, X1bf, X2bf,
                                           offs, eids, h_out, X1_out, X2_out, X1obf, X2obf);

    // ---- Q|K packed projections ----
    mm_bf16<0><<<dim3(1, 188), 256, 0, stream>>>(X1obf, 128, WA1T, nullptr, Q1K1,
                                                 128, 128, 0, np, nf, nu, nu, nf);
    mm_bf16<0><<<dim3(1, 313), 256, 0, stream>>>(X2obf, 128, WA2T, nullptr, Q2K2,
                                                 128, 128, 0, np, nf, nu, nu, nf);

    // ---- w ----
    w_kernel<<<NE / 4, 256, 0, stream>>>(Q1K1, Q2K2, edge, r1, r2, wbuf, NE);

    // ---- chained MLPs ----
    wchain_kernel<<<500, 256, 0, stream>>>(wbuf, Ww1T, Ww2T, bw1, bw2, wout);
    tchain_kernel<<<500, 256, 0, stream>>>(t_bf, Wt1T, Wt2T, bt1, bt2, t, wout, t_out);
}